// Round 4
// baseline (349.186 us; speedup 1.0000x reference)
//
#include <hip/hip_runtime.h>
#include <stdint.h>

typedef unsigned short u16;
typedef __bf16 bf16x8 __attribute__((ext_vector_type(8)));
typedef float f32x4 __attribute__((ext_vector_type(4)));

#define B_ 2
#define S_ 2048
#define H_ 2048
#define NH_ 16
#define HD_ 128

// softmax scale folded with log2(e): exp(s*scale) == exp2(s*SL2)
#define SL2f (0.08838834764831845f * 1.4426950408889634f)

__device__ __forceinline__ u16 f2bf(float f) {
    uint32_t u = __float_as_uint(f);
    u += 0x7fff + ((u >> 16) & 1);  // round-to-nearest-even
    return (u16)(u >> 16);
}

// async global->LDS, 16B per lane, LDS dest = wave-uniform base + lane*16
__device__ __forceinline__ void gl_lds16(const u16* g, u16* l) {
    __builtin_amdgcn_global_load_lds(
        (const __attribute__((address_space(1))) void*)g,
        (__attribute__((address_space(3))) void*)l, 16, 0, 0);
}

// ---------------- cast x (fp32 -> bf16) ----------------
__global__ __launch_bounds__(256) void cast_x_kernel(const float* __restrict__ x, u16* __restrict__ xb) {
    int i = (blockIdx.x * 256 + threadIdx.x) * 4;
    float4 v = *(const float4*)&x[i];
    ushort4 o;
    o.x = f2bf(v.x); o.y = f2bf(v.y); o.z = f2bf(v.z); o.w = f2bf(v.w);
    *(ushort4*)&xb[i] = o;
}

// ---------------- transpose + cast weights: Wt[n][k] = bf16(W[k][n]) ----------------
__global__ __launch_bounds__(256) void transpose_cast_kernel(
        const float* __restrict__ w0, const float* __restrict__ w1,
        const float* __restrict__ w2, const float* __restrict__ w3,
        u16* __restrict__ dqk, u16* __restrict__ dwv, u16* __restrict__ dwo) {
    int z = blockIdx.z;
    const float* src = (z == 0) ? w0 : (z == 1) ? w1 : (z == 2) ? w2 : w3;
    u16* dst = (z < 2) ? (dqk + (size_t)z * H_ * H_) : ((z == 2) ? dwv : dwo);
    __shared__ float tile[32][33];
    int n0 = blockIdx.x * 32, k0 = blockIdx.y * 32;
    int tx = threadIdx.x, ty = threadIdx.y;  // 32 x 8
#pragma unroll
    for (int i = 0; i < 4; i++)
        tile[ty + i * 8][tx] = src[(size_t)(k0 + ty + i * 8) * H_ + n0 + tx];
    __syncthreads();
#pragma unroll
    for (int i = 0; i < 4; i++)
        dst[(size_t)(n0 + ty + i * 8) * H_ + k0 + tx] = f2bf(tile[tx][ty + i * 8]);
}

// ---------------- GEMM: C[M,N] = A[M,K] @ Bt[N,K]^T  (bf16 in, fp32 acc) ----------------
// m97 structure: global_load_lds width-16 staging into unpadded XOR-swizzled LDS.
// MODE 0: N=4096 (Q|K). Scatter bf16 into Q (pre-scaled by SL2f) and K [B,NH,S,HD].
// MODE 1: fp32 row-major output [M,N].
// MODE 2: A=WvT (M=2048 dout), Bt=Xb (N=4096 tokens); write VT[b,h,d,s] (coalesced in s).
template <int MODE>
__global__ __launch_bounds__(256, 2) void gemm_bt(
        const u16* __restrict__ A, const u16* __restrict__ Bt, float* __restrict__ Cout,
        u16* __restrict__ q, u16* __restrict__ k, u16* __restrict__ v,
        int M, int N, int K) {
    __shared__ u16 As[128 * 64];
    __shared__ u16 Bs[128 * 64];
    int tid = threadIdx.x;
    int w = tid >> 6, lane = tid & 63, quad = lane >> 4, l16 = lane & 15;
    int wm = w >> 1, wn = w & 1;
    int m0 = blockIdx.y * 128, n0 = blockIdx.x * 128;

    f32x4 acc[4][4];
#pragma unroll
    for (int mi = 0; mi < 4; mi++)
#pragma unroll
        for (int ni = 0; ni < 4; ni++)
            acc[mi][ni] = (f32x4){0.f, 0.f, 0.f, 0.f};

    for (int k0 = 0; k0 < K; k0 += 64) {
        const u16* ga = A + (size_t)m0 * K + k0;
        const u16* gb = Bt + (size_t)n0 * K + k0;
#pragma unroll
        for (int j = 0; j < 4; j++) {
            int base = (j * 4 + w) * 64;
            int p = base + lane;
            int row = p >> 3;
            int c = (p & 7) ^ (row & 7);
            gl_lds16(&ga[(size_t)row * K + c * 8], &As[base * 8]);
            gl_lds16(&gb[(size_t)row * K + c * 8], &Bs[base * 8]);
        }
        __syncthreads();
#pragma unroll
        for (int ks = 0; ks < 2; ks++) {
            bf16x8 af[4], bf[4];
#pragma unroll
            for (int mi = 0; mi < 4; mi++) {
                int row = wm * 64 + mi * 16 + l16;
                af[mi] = *(const bf16x8*)&As[row * 64 + (((ks * 4 + quad) ^ (row & 7)) * 8)];
            }
#pragma unroll
            for (int ni = 0; ni < 4; ni++) {
                int row = wn * 64 + ni * 16 + l16;
                bf[ni] = *(const bf16x8*)&Bs[row * 64 + (((ks * 4 + quad) ^ (row & 7)) * 8)];
            }
#pragma unroll
            for (int mi = 0; mi < 4; mi++)
#pragma unroll
                for (int ni = 0; ni < 4; ni++)
                    acc[mi][ni] = __builtin_amdgcn_mfma_f32_16x16x32_bf16(af[mi], bf[ni], acc[mi][ni], 0, 0, 0);
        }
        __syncthreads();
    }

    // epilogue: D layout col = lane&15, row = quad*4 + r (m89-verified)
#pragma unroll
    for (int mi = 0; mi < 4; mi++) {
#pragma unroll
        for (int ni = 0; ni < 4; ni++) {
            int ng = n0 + wn * 64 + ni * 16 + l16;
#pragma unroll
            for (int r = 0; r < 4; r++) {
                int mg = m0 + wm * 64 + mi * 16 + quad * 4 + r;
                float val = acc[mi][ni][r];
                if (MODE == 0) {
                    int which = ng >> 11;          // 0=Q 1=K
                    int rem = ng & 2047;
                    int h = rem >> 7, d = rem & 127;
                    int b = mg >> 11, s = mg & 2047;
                    if (which == 0)
                        q[((size_t)((b * NH_ + h) * S_ + s)) * HD_ + d] = f2bf(val * SL2f);
                    else
                        k[((size_t)((b * NH_ + h) * S_ + s)) * HD_ + d] = f2bf(val);
                } else if (MODE == 2) {
                    int h = mg >> 7, d = mg & 127;  // mg = output dim
                    int b = ng >> 11, s = ng & 2047;  // ng = token
                    v[((size_t)((b * NH_ + h) * HD_ + d)) * S_ + s] = f2bf(val);
                } else {
                    Cout[(size_t)mg * N + ng] = val;
                }
            }
        }
    }
}

// ---------------- causal flash attention: paired q-tiles, DMA-staged, K double-buffered ----------------
// 512 blocks; block (b,h,pair) does q-tiles qt=pair and 31-pair -> exactly 33 kv-iters.
// LDS: Ks 2x16KB (dbuf DMA) + Vs 16KB (DMA from VT) + Ps 8KB = 56KB -> 2 blocks/CU.
// Q arrives pre-scaled by SL2f, so p = exp2(score) directly.
__global__ __launch_bounds__(256, 2) void flash_kernel(
        const u16* __restrict__ Q, const u16* __restrict__ Kb,
        const u16* __restrict__ VT, u16* __restrict__ Ctx) {
    __shared__ u16 Ks[2][64 * 128];  // [kv][d], chunk c at c ^ (kv&15)
    __shared__ u16 Vs[128 * 64];     // [d][kv], chunk c at c ^ (d&7)
    __shared__ u16 Ps[64 * 64];      // [qrow][kv], chunk c at c ^ (qrow&7)
    int tid = threadIdx.x;
    int w = tid >> 6, lane = tid & 63, quad = lane >> 4, l16 = lane & 15;

    int id = blockIdx.x;
    int bh = id & 31;
    int b = bh >> 4, h = bh & 15;
    int pair = id >> 5;              // 0..15
    int qts = pair, qtl = 31 - pair;
    int n0 = qts + 1;                // kv-tiles in segment 0; total always 33

    size_t bhoff = ((size_t)b * NH_ + h) * S_ * HD_;
    const u16* Qp = Q + bhoff;
    const u16* Kp = Kb + bhoff;
    const u16* Vp = VT + bhoff;      // [d][s]: d*2048 + s

    auto stageK = [&](int t, int buf) {
        int kv0 = ((t >= n0) ? (t - n0) : t) * 64;
#pragma unroll
        for (int j = 0; j < 4; j++) {
            int base = (j * 4 + w) * 64;
            int p = base + lane;
            int row = p >> 4;
            int c = (p & 15) ^ (row & 15);
            gl_lds16(&Kp[(size_t)(kv0 + row) * HD_ + c * 8], &Ks[buf][base * 8]);
        }
    };
    auto stageV = [&](int t) {
        int kv0 = ((t >= n0) ? (t - n0) : t) * 64;
#pragma unroll
        for (int j = 0; j < 4; j++) {
            int base = (j * 4 + w) * 64;
            int p = base + lane;
            int row = p >> 3;
            int c = (p & 7) ^ (row & 7);
            gl_lds16(&Vp[(size_t)row * S_ + kv0 + c * 8], &Vs[base * 8]);
        }
    };

    int q0 = qts * 64, qw = q0 + w * 16;
    bf16x8 qf[4];
#pragma unroll
    for (int ks = 0; ks < 4; ks++)
        qf[ks] = *(const bf16x8*)&Qp[(size_t)(qw + l16) * HD_ + ks * 32 + quad * 8];

    float l_part[4] = {0.f, 0.f, 0.f, 0.f};
    f32x4 ao[8];
#pragma unroll
    for (int dt = 0; dt < 8; dt++) ao[dt] = (f32x4){0.f, 0.f, 0.f, 0.f};

    auto epilogue = [&]() {
#pragma unroll
        for (int r = 0; r < 4; r++) {
            float l = l_part[r];
            l += __shfl_xor(l, 1);
            l += __shfl_xor(l, 2);
            l += __shfl_xor(l, 4);
            l += __shfl_xor(l, 8);
            float inv = 1.0f / l;
            int qg = qw + quad * 4 + r;
            size_t rowbase = ((size_t)b * S_ + qg) * H_ + h * HD_;
#pragma unroll
            for (int dt = 0; dt < 8; dt++)
                Ctx[rowbase + dt * 16 + l16] = f2bf(ao[dt][r] * inv);
        }
    };

    stageK(0, 0);  // prologue; drained at first barrier

    for (int t = 0; t < 33; t++) {
        __syncthreads();                 // drains K(t) DMA; prev readers done
        if (t + 1 < 33) stageK(t + 1, (t + 1) & 1);
        stageV(t);
        if (t == n0) {                   // segment switch: finish qts, start qtl
            epilogue();
            q0 = qtl * 64; qw = q0 + w * 16;
#pragma unroll
            for (int ks = 0; ks < 4; ks++)
                qf[ks] = *(const bf16x8*)&Qp[(size_t)(qw + l16) * HD_ + ks * 32 + quad * 8];
#pragma unroll
            for (int r = 0; r < 4; r++) l_part[r] = 0.f;
#pragma unroll
            for (int dt = 0; dt < 8; dt++) ao[dt] = (f32x4){0.f, 0.f, 0.f, 0.f};
        }
        int kv0 = ((t >= n0) ? (t - n0) : t) * 64;
        bool diag = (t == n0 - 1) || (t == 32);   // kv0 == q0 only on these
        int buf = t & 1;

        // --- S = Q K^T (score pre-scaled via Q) ---
        f32x4 sc[4];
#pragma unroll
        for (int nt = 0; nt < 4; nt++) {
            sc[nt] = (f32x4){0.f, 0.f, 0.f, 0.f};
            int row = nt * 16 + l16;
#pragma unroll
            for (int ks = 0; ks < 4; ks++) {
                bf16x8 kf = *(const bf16x8*)&Ks[buf][row * 128 + (((ks * 4 + quad) ^ (row & 15)) * 8)];
                sc[nt] = __builtin_amdgcn_mfma_f32_16x16x32_bf16(qf[ks], kf, sc[nt], 0, 0, 0);
            }
        }

        // --- softmax (no running max; causal mask only on diag tiles) + P -> LDS ---
        if (!diag) {
#pragma unroll
            for (int r = 0; r < 4; r++) {
                int prow = w * 16 + quad * 4 + r;
                float psum = 0.f;
#pragma unroll
                for (int nt = 0; nt < 4; nt++) {
                    float p = exp2f(sc[nt][r]);
                    sc[nt][r] = p;
                    psum += p;
                }
                l_part[r] += psum;
#pragma unroll
                for (int nt = 0; nt < 4; nt++) {
                    int col = nt * 16 + l16;
                    Ps[prow * 64 + (((col >> 3) ^ (prow & 7)) * 8) + (col & 7)] = f2bf(sc[nt][r]);
                }
            }
        } else {
#pragma unroll
            for (int r = 0; r < 4; r++) {
                int prow = w * 16 + quad * 4 + r;
                int qg = qw + quad * 4 + r;
                float psum = 0.f;
#pragma unroll
                for (int nt = 0; nt < 4; nt++) {
                    float p = (kv0 + nt * 16 + l16 > qg) ? 0.f : exp2f(sc[nt][r]);
                    sc[nt][r] = p;
                    psum += p;
                }
                l_part[r] += psum;
#pragma unroll
                for (int nt = 0; nt < 4; nt++) {
                    int col = nt * 16 + l16;
                    Ps[prow * 64 + (((col >> 3) ^ (prow & 7)) * 8) + (col & 7)] = f2bf(sc[nt][r]);
                }
            }
        }

        __syncthreads();                 // drains V(t) DMA (hidden under QK+softmax)

        // --- O += P @ V ---
#pragma unroll
        for (int kstep = 0; kstep < 2; kstep++) {
            int prow = w * 16 + l16;
            bf16x8 pf = *(const bf16x8*)&Ps[prow * 64 + (((kstep * 4 + quad) ^ (prow & 7)) * 8)];
#pragma unroll
            for (int dt = 0; dt < 8; dt++) {
                int d = dt * 16 + l16;
                bf16x8 vf = *(const bf16x8*)&Vs[d * 64 + (((kstep * 4 + quad) ^ (d & 7)) * 8)];
                ao[dt] = __builtin_amdgcn_mfma_f32_16x16x32_bf16(pf, vf, ao[dt], 0, 0, 0);
            }
        }
    }
    epilogue();
}

extern "C" void kernel_launch(void* const* d_in, const int* in_sizes, int n_in,
                              void* d_out, int out_size, void* d_ws, size_t ws_size,
                              hipStream_t stream) {
    const float* x  = (const float*)d_in[0];
    const float* Wq = (const float*)d_in[1];
    const float* Wk = (const float*)d_in[2];
    const float* Wv = (const float*)d_in[3];
    const float* Wo = (const float*)d_in[4];
    float* out = (float*)d_out;

    const size_t MB = 1024 * 1024;
    char* ws = (char*)d_ws;
    u16* Xb   = (u16*)(ws);            // 16 MB : x bf16 [4096,2048]
    u16* WqkT = (u16*)(ws + 16 * MB);  // 16 MB : [4096,2048] (Wq^T;Wk^T)
    u16* WvT  = (u16*)(ws + 32 * MB);  //  8 MB : [2048,2048]
    u16* WoT  = (u16*)(ws + 40 * MB);  //  8 MB
    u16* Qb   = (u16*)(ws + 48 * MB);  // 16 MB : [B,NH,S,HD], pre-scaled
    u16* Kbuf = (u16*)(ws + 64 * MB);  // 16 MB : [B,NH,S,HD]
    u16* VT   = (u16*)(ws + 80 * MB);  // 16 MB : [B,NH,HD,S]  (written directly by MODE 2)
    u16* Ctx  = (u16*)(ws + 96 * MB);  // 16 MB : [4096,2048] attn output

    cast_x_kernel<<<8192, 256, 0, stream>>>(x, Xb);
    transpose_cast_kernel<<<dim3(64, 64, 4), dim3(32, 8), 0, stream>>>(Wq, Wk, Wv, Wo, WqkT, WvT, WoT);
    gemm_bt<0><<<dim3(32, 32), 256, 0, stream>>>(Xb, WqkT, nullptr, Qb, Kbuf, nullptr, 4096, 4096, 2048);
    gemm_bt<2><<<dim3(32, 16), 256, 0, stream>>>(WvT, Xb, nullptr, nullptr, nullptr, VT, 2048, 4096, 2048);
    flash_kernel<<<512, 256, 0, stream>>>(Qb, Kbuf, VT, Ctx);
    gemm_bt<1><<<dim3(16, 32), 256, 0, stream>>>(Ctx, WoT, out, nullptr, nullptr, nullptr, 4096, 2048, 2048);
}